// Round 5
// baseline (3350.855 us; speedup 1.0000x reference)
//
#include <hip/hip_runtime.h>
#include <hip/hip_bf16.h>
#include <stdint.h>

#define E_ 8
#define L_ 12
#define D_ 768
#define H_ 12
#define S_ 512
#define B_ 32
#define BS_ (B_*S_)   // 16384

typedef __attribute__((ext_vector_type(4))) float floatx4;
typedef __attribute__((ext_vector_type(8))) __bf16 bf16x8;
typedef __attribute__((ext_vector_type(4))) __bf16 bf16x4;

__device__ __forceinline__ __bf16 f2bf(float f) {
  unsigned u = __builtin_bit_cast(unsigned, f);
  u += 0x7fffu + ((u >> 16) & 1u);           // RNE
  unsigned short h = (unsigned short)(u >> 16);
  return __builtin_bit_cast(__bf16, h);
}

__device__ __forceinline__ float fexp2(float x) {
#if __has_builtin(__builtin_amdgcn_exp2f)
  return __builtin_amdgcn_exp2f(x);
#else
  return exp2f(x);
#endif
}

__device__ __forceinline__ void async16(const void* g, void* l) {
  __builtin_amdgcn_global_load_lds((__attribute__((address_space(1))) void*)g,
                                   (__attribute__((address_space(3))) void*)l,
                                   16, 0, 0);
}

// ---------------- routing stage 1: 64 blocks x 8 rows, coalesced partial sums ----------------
__global__ void routing_pool_kernel(const float* __restrict__ hidden,
                                    float* __restrict__ partial) {
  const int blk = blockIdx.x;    // 0..63
  const int tid = threadIdx.x;
  const float* base = hidden + (size_t)(B_-1)*S_*D_ + (size_t)blk*8*D_;
  float acc[3] = {0.f, 0.f, 0.f};
  for (int s = 0; s < 8; ++s) {
#pragma unroll
    for (int i = 0; i < 3; ++i)
      acc[i] += base[(size_t)s*D_ + tid + i*256];
  }
#pragma unroll
  for (int i = 0; i < 3; ++i) partial[(size_t)blk*D_ + tid + i*256] = acc[i];
}

// ---------------- routing stage 2: reduce partials, logits, argmax ----------------
__global__ void routing_finish_kernel(const float* __restrict__ partial,
                                      const float* __restrict__ rw,
                                      int* __restrict__ e_out) {
  __shared__ float pooled[D_];
  __shared__ float logits[E_];
  int tid = threadIdx.x;
#pragma unroll
  for (int i = 0; i < 3; ++i) {
    int d = tid + i*256;
    float s = 0.f;
    for (int blk = 0; blk < 64; ++blk) s += partial[(size_t)blk*D_ + d];
    pooled[d] = s;  // positive scale factor irrelevant for argmax
  }
  __syncthreads();
  if (tid < E_) {
    float s = 0.f;
    for (int d = 0; d < D_; ++d) s += pooled[d] * rw[d*E_ + tid];
    logits[tid] = s;
  }
  __syncthreads();
  if (tid == 0) {
    int best = 0; float bvv = logits[0];
    for (int e = 1; e < E_; ++e) if (logits[e] > bvv) { bvv = logits[e]; best = e; }
    e_out[0] = best;
  }
}

// ---------------- fp32 -> bf16 convert (n multiple of 2048) ----------------
__global__ void convert_bf16_kernel(const float* __restrict__ src, __bf16* __restrict__ dst) {
  size_t i = ((size_t)blockIdx.x*256 + threadIdx.x)*8;
  __bf16 r[8];
#pragma unroll
  for (int j = 0; j < 8; ++j) r[j] = f2bf(src[i+j]);
  *(bf16x8*)(dst + i) = *(bf16x8*)r;
}

// Wk [L][768][768] fp32 -> rows 768..1535 of wqkv [L][2304][768] bf16
__global__ void convert_wk_kernel(const float* __restrict__ wk, __bf16* __restrict__ wqkv) {
  size_t i = ((size_t)blockIdx.x*256 + threadIdx.x)*8;
  int l = (int)(i / (D_*D_));
  int rem = (int)(i % (D_*D_));
  int n = rem / D_, k = rem % D_;
  __bf16 r[8];
#pragma unroll
  for (int j = 0; j < 8; ++j) r[j] = f2bf(wk[i+j]);
  *(bf16x8*)(wqkv + (size_t)l*2304*D_ + (size_t)(768+n)*D_ + k) = *(bf16x8*)r;
}

// ---------------- TT adapter build: Wq_a / Wv_a -> wqkv bf16 ----------------
__global__ void tt_prep_kernel(
    const float* __restrict__ qc0, const float* __restrict__ qc1, const float* __restrict__ qc2,
    const float* __restrict__ qc3, const float* __restrict__ qc4, const float* __restrict__ qc5,
    const float* __restrict__ vc0, const float* __restrict__ vc1, const float* __restrict__ vc2,
    const float* __restrict__ vc3, const float* __restrict__ vc4, const float* __restrict__ vc5,
    const float* __restrict__ Wq, const float* __restrict__ Wv,
    const int* __restrict__ e_idx, __bf16* __restrict__ wqkv) {
  const int l = blockIdx.x;
  const int pre = blockIdx.y;         // 0 = q, 1 = v
  const int z = blockIdx.z;           // 0..15 -> rows 48z..48z+47
  const int tid = threadIdx.x;
  const int e = e_idx[0];
  const float* c0 = (pre ? vc0 : qc0) + (size_t)(e*L_ + l)*96;   // [12][8]
  const float* c1 = (pre ? vc1 : qc1) + (size_t)(e*L_ + l)*512;  // [8][8][8]
  const float* c2 = (pre ? vc2 : qc2) + (size_t)(e*L_ + l)*512;
  const float* c3 = (pre ? vc3 : qc3) + (size_t)(e*L_ + l)*512;
  const float* c4 = (pre ? vc4 : qc4) + (size_t)(e*L_ + l)*512;
  const float* c5 = (pre ? vc5 : qc5) + (size_t)(e*L_ + l)*96;   // [8][12]
  __shared__ float M1[768];   // [j][l2][m]
  __shared__ float R2[768];   // [q][r][t]
  __shared__ float M2[6144];  // [out][o]
  __shared__ float Rm[6144];  // [o][in]
  for (int idx = tid; idx < 768; idx += 256) {
    int j = idx >> 6, rem = idx & 63, l2 = rem >> 3, m = rem & 7;
    float s = 0.f;
    for (int k = 0; k < 8; ++k) s += c0[j*8 + k] * c1[k*64 + l2*8 + m];
    M1[idx] = s;
    int qq = idx / 96, rem2 = idx % 96, rr = rem2 / 12, t = rem2 % 12;
    float s2 = 0.f;
    for (int si = 0; si < 8; ++si) s2 += c4[qq*64 + rr*8 + si] * c5[si*12 + t];
    R2[idx] = s2;
  }
  __syncthreads();
  for (int idx = tid; idx < 6144; idx += 256) {
    int o = idx & 7, n = (idx >> 3) & 7, jl = idx >> 6;
    float s = 0.f;
    for (int m = 0; m < 8; ++m) s += M1[jl*8 + m] * c2[m*64 + n*8 + o];
    M2[idx] = s;
    int o2 = idx / 768, inp = idx % 768, p = inp / 96, rt = inp % 96;
    float s2 = 0.f;
    for (int qq = 0; qq < 8; ++qq) s2 += c3[o2*64 + p*8 + qq] * R2[qq*96 + rt];
    Rm[idx] = s2;
  }
  __syncthreads();
  const float* Wbase = (pre ? Wv : Wq) + (size_t)l*D_*D_;
  __bf16* dst = wqkv + (size_t)l*2304*D_ + (pre ? (size_t)1536*D_ : 0);
  for (int g = tid; g < 48*96; g += 256) {
    const int outr = z*48 + (g / 96);
    const int inp0 = (g % 96) * 8;
    float m2r[8];
#pragma unroll
    for (int o = 0; o < 8; ++o) m2r[o] = M2[outr*8 + o];
    float acc[8];
#pragma unroll
    for (int u = 0; u < 8; ++u) acc[u] = 0.f;
#pragma unroll
    for (int o = 0; o < 8; ++o) {
      float4 r0 = *(const float4*)&Rm[o*768 + inp0];
      float4 r1 = *(const float4*)&Rm[o*768 + inp0 + 4];
      acc[0] += m2r[o]*r0.x; acc[1] += m2r[o]*r0.y;
      acc[2] += m2r[o]*r0.z; acc[3] += m2r[o]*r0.w;
      acc[4] += m2r[o]*r1.x; acc[5] += m2r[o]*r1.y;
      acc[6] += m2r[o]*r1.z; acc[7] += m2r[o]*r1.w;
    }
    const float* wb = Wbase + (size_t)outr*768 + inp0;
    float4 w0 = *(const float4*)wb;
    float4 w1 = *(const float4*)(wb + 4);
    __bf16 r[8];
    r[0] = f2bf(w0.x + 8.f*acc[0]); r[1] = f2bf(w0.y + 8.f*acc[1]);
    r[2] = f2bf(w0.z + 8.f*acc[2]); r[3] = f2bf(w0.w + 8.f*acc[3]);
    r[4] = f2bf(w1.x + 8.f*acc[4]); r[5] = f2bf(w1.y + 8.f*acc[5]);
    r[6] = f2bf(w1.z + 8.f*acc[6]); r[7] = f2bf(w1.w + 8.f*acc[7]);
    *(bf16x8*)(dst + (size_t)outr*768 + inp0) = *(bf16x8*)r;
  }
}

// ---------------- bf16 MFMA GEMM, XCD-swizzled 1-D grid ----------------
// n&7 = XCD slot; each XCD owns 16 M-tiles (A stays L2-resident, ~3.1 MB)
// and sweeps N-tiles outer / M-tiles inner (weight tile hot across 16 blocks).
// OUTBF path (QKV gemm): nblk<12 -> q/k into qkv; nblk>=12 -> V transposed into vt.
template<bool OUTBF>
__global__ __launch_bounds__(256) void gemm_bt(
    const __bf16* __restrict__ A, const __bf16* __restrict__ Bw,
    const float* __restrict__ bq, const float* __restrict__ bk, const float* __restrict__ bvp,
    __bf16* __restrict__ outb, float* __restrict__ outf, __bf16* __restrict__ vtout, int Nw) {
  const int K = D_;
  __shared__ __align__(16) __bf16 As[128*64];
  __shared__ __align__(16) __bf16 Bs[128*64];
  const int tid = threadIdx.x;
  const int w = tid >> 6, lane = tid & 63;
  const int quad = lane >> 4, l16 = lane & 15;
  const int wr = w >> 1, wc = w & 1;
  const int n = blockIdx.x;
  const int slot = n & 7, g = n >> 3;
  const int nblk_i = g >> 4;                 // N-tile index (outer)
  const int mblk_i = slot*16 + (g & 15);     // M-tile: 16 per XCD slot (inner)
  const size_t mblk = (size_t)mblk_i * 128;
  const size_t nblk = (size_t)nblk_i * 128;
  const __bf16* Ab = A + mblk * K;
  const __bf16* Bb = Bw + nblk * K;
  const int lrow = lane >> 3;        // 0..7
  const int scol = (lane & 7) * 8;   // element offset in K
  floatx4 acc[4][4];
#pragma unroll
  for (int i = 0; i < 4; ++i)
#pragma unroll
    for (int j = 0; j < 4; ++j) acc[i][j] = {0.f,0.f,0.f,0.f};

  for (int k0 = 0; k0 < K; k0 += 64) {
    __syncthreads();
#pragma unroll
    for (int i = 0; i < 4; ++i) {
      const int chunk = w*4 + i;           // wave-uniform
      const int row = chunk*8 + lrow;
      async16(Ab + (size_t)row*K + k0 + scol, &As[chunk*512]);
      async16(Bb + (size_t)row*K + k0 + scol, &Bs[chunk*512]);
    }
    __syncthreads();
#pragma unroll
    for (int kk = 0; kk < 64; kk += 32) {
      bf16x8 af[4], bfr[4];
#pragma unroll
      for (int i = 0; i < 4; ++i) af[i]  = *(const bf16x8*)&As[(wr*64 + i*16 + l16)*64 + kk + quad*8];
#pragma unroll
      for (int j = 0; j < 4; ++j) bfr[j] = *(const bf16x8*)&Bs[(wc*64 + j*16 + l16)*64 + kk + quad*8];
#pragma unroll
      for (int i = 0; i < 4; ++i)
#pragma unroll
        for (int j = 0; j < 4; ++j)
          acc[i][j] = __builtin_amdgcn_mfma_f32_16x16x32_bf16(af[i], bfr[j], acc[i][j], 0, 0, 0);
    }
  }
  if (OUTBF && nblk_i >= 12) {
    // V block: bias + transpose-write straight into vt[bh][64][512]
#pragma unroll
    for (int j = 0; j < 4; ++j) {
      const int vcol = (int)nblk - 1536 + wc*64 + j*16 + l16;   // 0..767
      const int h = vcol >> 6, d = vcol & 63;
      const float bval = bvp[vcol];
#pragma unroll
      for (int i = 0; i < 4; ++i) {
        const int mrow = (int)mblk + wr*64 + i*16 + quad*4;     // r=0 base
        const int b = mrow >> 9, s = mrow & 511;
        __bf16 pr[4];
#pragma unroll
        for (int r = 0; r < 4; ++r) pr[r] = f2bf(acc[i][j][r] + bval);
        *(bf16x4*)(vtout + (size_t)((b*H_ + h)*64 + d)*S_ + s) = *(bf16x4*)pr;
      }
    }
    return;
  }
  const float* bias = bq;
  if (Nw == 2304) bias = (nblk_i < 6) ? bq : bk;
#pragma unroll
  for (int i = 0; i < 4; ++i) {
#pragma unroll
    for (int j = 0; j < 4; ++j) {
      const int ncol = (int)nblk + wc*64 + j*16 + l16;
      const float bval = bias[ncol % 768];
#pragma unroll
      for (int r = 0; r < 4; ++r) {
        const int mrow = (int)mblk + wr*64 + i*16 + quad*4 + r;
        float v = acc[i][j][r] + bval;
        if (OUTBF) outb[(size_t)mrow*Nw + ncol] = f2bf(v);
        else       outf[(size_t)mrow*Nw + ncol] = v;
      }
    }
  }
}

// ---------------- flash attention v3: 2 Q-tiles per block ----------------
// grid 1536: slot=n&7 (XCD); g=n>>3; bh=(g>>2)*8+slot; q-pair=(g&3) -> q0=128*(g&3).
// K/V staged once per kt for both Q-tiles; Ps reused across tiles (same-wave DS in-order).
#define PSTR 72   // padded LDS row stride (bf16): 144 B -> bank-even b128 access
__global__ __launch_bounds__(256) void flash_kernel(const __bf16* __restrict__ qkv,
                                                    const __bf16* __restrict__ vt,
                                                    __bf16* __restrict__ ctx) {
  __shared__ __align__(16) __bf16 Qs[128*PSTR];   // [q][d], two 64-row tiles
  __shared__ __align__(16) __bf16 Ks[64*PSTR];    // [kv][d]
  __shared__ __align__(16) __bf16 Vts[64*PSTR];   // [d][kv]
  __shared__ __align__(16) __bf16 Ps[64*PSTR];    // [q][kv], wave w owns rows w*16..+15
  const int tid = threadIdx.x;
  const int w = tid >> 6, lane = tid & 63;
  const int quad = lane >> 4, l16 = lane & 15;
  const int n = blockIdx.x;
  const int slot = n & 7, g = n >> 3;
  const int bh = (g >> 2)*8 + slot;
  const int q0 = (g & 3) * 128;
  const int b = bh / H_, h = bh % H_;
  const float SCL = 0.125f * 1.44269504f;  // 1/sqrt(64) * log2(e)

  // stage both Q tiles: 1024 slots (row 0..127, seg 0..7), 4 per thread
#pragma unroll
  for (int it = 0; it < 4; ++it) {
    int sl = it*256 + tid, row = sl >> 3, seg = sl & 7;
    bf16x8 v = *(const bf16x8*)(qkv + (size_t)(b*S_ + q0 + row)*2304 + h*64 + seg*8);
    *(bf16x8*)&Qs[row*PSTR + seg*8] = v;
  }

  floatx4 acc_o[2][4];   // [tile][d-group], C[m=q_local][n=d]
#pragma unroll
  for (int t = 0; t < 2; ++t)
#pragma unroll
    for (int jd = 0; jd < 4; ++jd) acc_o[t][jd] = {0.f,0.f,0.f,0.f};
  float m_prev[2] = {-__builtin_inff(), -__builtin_inff()};
  float l_part[2] = {0.f, 0.f};

  for (int kt = 0; kt < 8; ++kt) {
    __syncthreads();
#pragma unroll
    for (int it = 0; it < 2; ++it) {
      int sl = it*256 + tid, row = sl >> 3, seg = sl & 7;
      bf16x8 kvv = *(const bf16x8*)(qkv + (size_t)(b*S_ + kt*64 + row)*2304 + 768 + h*64 + seg*8);
      bf16x8 vtv = *(const bf16x8*)(vt + (size_t)(bh*64 + row)*S_ + kt*64 + seg*8);
      *(bf16x8*)&Ks[row*PSTR + seg*8] = kvv;
      *(bf16x8*)&Vts[row*PSTR + seg*8] = vtv;
    }
    __syncthreads();
#pragma unroll
    for (int t = 0; t < 2; ++t) {
      // S^T tile: mfma(A=K, B=Q_t) -> C[m=kv=i*16+quad*4+r][n=q=w*16+l16]
      floatx4 sacc[4];
#pragma unroll
      for (int i = 0; i < 4; ++i) sacc[i] = {0.f,0.f,0.f,0.f};
#pragma unroll
      for (int kk = 0; kk < 64; kk += 32) {
        bf16x8 bq_ = *(const bf16x8*)&Qs[(t*64 + w*16 + l16)*PSTR + kk + quad*8];
#pragma unroll
        for (int i = 0; i < 4; ++i) {
          bf16x8 ak = *(const bf16x8*)&Ks[(i*16 + l16)*PSTR + kk + quad*8];
          sacc[i] = __builtin_amdgcn_mfma_f32_16x16x32_bf16(ak, bq_, sacc[i], 0, 0, 0);
        }
      }
      float sv[4][4];
#pragma unroll
      for (int i = 0; i < 4; ++i)
#pragma unroll
        for (int r = 0; r < 4; ++r) sv[i][r] = sacc[i][r] * SCL;
      float mloc = sv[0][0];
#pragma unroll
      for (int i = 0; i < 4; ++i)
#pragma unroll
        for (int r = 0; r < 4; ++r) mloc = fmaxf(mloc, sv[i][r]);
      mloc = fmaxf(mloc, __shfl_xor(mloc, 16));
      mloc = fmaxf(mloc, __shfl_xor(mloc, 32));
      float mnew = fmaxf(m_prev[t], mloc);
      float alpha = fexp2(m_prev[t] - mnew);
      m_prev[t] = mnew;
      float rsum = 0.f;
#pragma unroll
      for (int i = 0; i < 4; ++i) {
        __bf16 pr[4];
#pragma unroll
        for (int r = 0; r < 4; ++r) {
          float p = fexp2(sv[i][r] - mnew);
          rsum += p;
          pr[r] = f2bf(p);
        }
        *(bf16x4*)&Ps[(w*16 + l16)*PSTR + i*16 + quad*4] = *(bf16x4*)pr;  // b64, bank-even
      }
      l_part[t] = l_part[t]*alpha + rsum;
      float ab[4];
#pragma unroll
      for (int r = 0; r < 4; ++r) ab[r] = __shfl(alpha, quad*4 + r);
#pragma unroll
      for (int jd = 0; jd < 4; ++jd)
#pragma unroll
        for (int r = 0; r < 4; ++r) acc_o[t][jd][r] *= ab[r];
      // O_t += P V : same-wave ds write->read (and read->next-write) in-order
#pragma unroll
      for (int kk = 0; kk < 64; kk += 32) {
        bf16x8 ap = *(const bf16x8*)&Ps[(w*16 + l16)*PSTR + kk + quad*8];
#pragma unroll
        for (int jd = 0; jd < 4; ++jd) {
          bf16x8 bv_ = *(const bf16x8*)&Vts[(jd*16 + l16)*PSTR + kk + quad*8];
          acc_o[t][jd] = __builtin_amdgcn_mfma_f32_16x16x32_bf16(ap, bv_, acc_o[t][jd], 0, 0, 0);
        }
      }
    }
  }
#pragma unroll
  for (int t = 0; t < 2; ++t) {
    float l_tot = l_part[t];
    l_tot += __shfl_xor(l_tot, 16);
    l_tot += __shfl_xor(l_tot, 32);
    float lb[4];
#pragma unroll
    for (int r = 0; r < 4; ++r) lb[r] = __shfl(l_tot, quad*4 + r);
#pragma unroll
    for (int jd = 0; jd < 4; ++jd) {
      const int d = jd*16 + l16;
#pragma unroll
      for (int r = 0; r < 4; ++r) {
        const int q = q0 + t*64 + w*16 + quad*4 + r;
        ctx[(size_t)(b*S_ + q)*D_ + h*64 + d] = f2bf(acc_o[t][jd][r] / lb[r]);
      }
    }
  }
}

// ---------------- residual + LayerNorm (fp32), writes fp32 master + bf16 copy ----------------
__global__ __launch_bounds__(256) void ln_kernel(const float* __restrict__ resid,
                                                 const float* __restrict__ proj,
                                                 const float* __restrict__ gamma,
                                                 const float* __restrict__ beta,
                                                 float* __restrict__ xout,
                                                 __bf16* __restrict__ xbf) {
  const int row = blockIdx.x;
  const int tid = threadIdx.x;
  const int w = tid >> 6, lane = tid & 63;
  __shared__ float red[4];
  float v[3]; int dd[3];
#pragma unroll
  for (int i = 0; i < 3; ++i) {
    int d = tid + i*256; dd[i] = d;
    v[i] = resid[(size_t)row*D_ + d] + proj[(size_t)row*D_ + d];
  }
  float s = v[0] + v[1] + v[2];
#pragma unroll
  for (int off = 32; off; off >>= 1) s += __shfl_xor(s, off);
  if (lane == 0) red[w] = s;
  __syncthreads();
  float mu = (red[0]+red[1]+red[2]+red[3]) * (1.f/768.f);
  __syncthreads();
  float q = 0.f;
#pragma unroll
  for (int i = 0; i < 3; ++i) { float d = v[i]-mu; q += d*d; }
#pragma unroll
  for (int off = 32; off; off >>= 1) q += __shfl_xor(q, off);
  if (lane == 0) red[w] = q;
  __syncthreads();
  float var = (red[0]+red[1]+red[2]+red[3]) * (1.f/768.f);
  float rs = rsqrtf(var + 1e-12f);
#pragma unroll
  for (int i = 0; i < 3; ++i) {
    float o = (v[i]-mu)*rs*gamma[dd[i]] + beta[dd[i]];
    xout[(size_t)row*D_ + dd[i]] = o;
    xbf[(size_t)row*D_ + dd[i]] = f2bf(o);
  }
}

extern "C" void kernel_launch(void* const* d_in, const int* in_sizes, int n_in,
                              void* d_out, int out_size, void* d_ws, size_t ws_size,
                              hipStream_t stream) {
  const float* hidden = (const float*)d_in[0];
  const float* router = (const float*)d_in[1];
  const float* qc[6]; const float* vc[6];
  for (int i = 0; i < 6; ++i) qc[i] = (const float*)d_in[2+i];
  for (int i = 0; i < 6; ++i) vc[i] = (const float*)d_in[8+i];
  const float* Wq = (const float*)d_in[14];
  const float* Wk = (const float*)d_in[15];
  const float* Wv = (const float*)d_in[16];
  const float* Wo = (const float*)d_in[17];
  const float* bq = (const float*)d_in[18];
  const float* bk = (const float*)d_in[19];
  const float* bv = (const float*)d_in[20];
  const float* bo = (const float*)d_in[21];
  const float* lns = (const float*)d_in[22];
  const float* lnb = (const float*)d_in[23];
  float* out = (float*)d_out;

  char* ws = (char*)d_ws;
  size_t off = 0;
  auto alloc = [&](size_t bytes) -> void* {
    off = (off + 255) & ~(size_t)255;
    void* p = ws + off; off += bytes; return p;
  };
  int*    e_idx = (int*)   alloc(4);
  float*  rpart = (float*) alloc((size_t)64*D_*4);
  __bf16* xbf   = (__bf16*)alloc((size_t)BS_*D_*2);
  __bf16* qkv   = (__bf16*)alloc((size_t)BS_*2304*2);
  __bf16* vt    = (__bf16*)alloc((size_t)B_*H_*64*S_*2);
  __bf16* ctx   = (__bf16*)alloc((size_t)BS_*D_*2);
  float*  proj  = (float*) alloc((size_t)BS_*D_*4);
  __bf16* wqkv  = (__bf16*)alloc((size_t)L_*2304*D_*2);
  __bf16* wobf  = (__bf16*)alloc((size_t)L_*D_*D_*2);
  (void)ws_size; (void)in_sizes; (void)n_in; (void)out_size;

  routing_pool_kernel<<<64, 256, 0, stream>>>(hidden, rpart);
  routing_finish_kernel<<<1, 256, 0, stream>>>(rpart, router, e_idx);
  convert_bf16_kernel<<<(BS_*D_)/2048, 256, 0, stream>>>(hidden, xbf);
  tt_prep_kernel<<<dim3(L_, 2, 16), 256, 0, stream>>>(qc[0],qc[1],qc[2],qc[3],qc[4],qc[5],
                                                      vc[0],vc[1],vc[2],vc[3],vc[4],vc[5],
                                                      Wq, Wv, e_idx, wqkv);
  convert_wk_kernel<<<(L_*D_*D_)/2048, 256, 0, stream>>>(Wk, wqkv);
  convert_bf16_kernel<<<(L_*D_*D_)/2048, 256, 0, stream>>>(Wo, wobf);

  for (int l = 0; l < L_; ++l) {
    gemm_bt<true><<<2304, 256, 0, stream>>>(xbf, wqkv + (size_t)l*2304*D_,
        bq + l*D_, bk + l*D_, bv + l*D_, qkv, nullptr, vt, 2304);
    flash_kernel<<<1536, 256, 0, stream>>>(qkv, vt, ctx);
    gemm_bt<false><<<768, 256, 0, stream>>>(ctx, wobf + (size_t)l*D_*D_,
        bo + l*D_, nullptr, nullptr, nullptr, proj, nullptr, 768);
    ln_kernel<<<BS_, 256, 0, stream>>>(l == 0 ? hidden : out, proj,
        lns + l*D_, lnb + l*D_, out, xbf);
  }
}

// Round 6
// 3050.903 us; speedup vs baseline: 1.0983x; 1.0983x over previous
//
#include <hip/hip_runtime.h>
#include <hip/hip_bf16.h>
#include <stdint.h>

#define E_ 8
#define L_ 12
#define D_ 768
#define H_ 12
#define S_ 512
#define B_ 32
#define BS_ (B_*S_)   // 16384

typedef __attribute__((ext_vector_type(4))) float floatx4;
typedef __attribute__((ext_vector_type(8))) __bf16 bf16x8;
typedef __attribute__((ext_vector_type(4))) __bf16 bf16x4;

__device__ __forceinline__ __bf16 f2bf(float f) {
  unsigned u = __builtin_bit_cast(unsigned, f);
  u += 0x7fffu + ((u >> 16) & 1u);           // RNE
  unsigned short h = (unsigned short)(u >> 16);
  return __builtin_bit_cast(__bf16, h);
}

__device__ __forceinline__ float fexp2(float x) {
#if __has_builtin(__builtin_amdgcn_exp2f)
  return __builtin_amdgcn_exp2f(x);
#else
  return exp2f(x);
#endif
}

__device__ __forceinline__ void async16(const void* g, void* l) {
  __builtin_amdgcn_global_load_lds((__attribute__((address_space(1))) void*)g,
                                   (__attribute__((address_space(3))) void*)l,
                                   16, 0, 0);
}

// ---------------- routing stage 1: 64 blocks x 8 rows, coalesced partial sums ----------------
__global__ void routing_pool_kernel(const float* __restrict__ hidden,
                                    float* __restrict__ partial) {
  const int blk = blockIdx.x;    // 0..63
  const int tid = threadIdx.x;
  const float* base = hidden + (size_t)(B_-1)*S_*D_ + (size_t)blk*8*D_;
  float acc[3] = {0.f, 0.f, 0.f};
  for (int s = 0; s < 8; ++s) {
#pragma unroll
    for (int i = 0; i < 3; ++i)
      acc[i] += base[(size_t)s*D_ + tid + i*256];
  }
#pragma unroll
  for (int i = 0; i < 3; ++i) partial[(size_t)blk*D_ + tid + i*256] = acc[i];
}

// ---------------- routing stage 2: reduce partials, logits, argmax ----------------
__global__ void routing_finish_kernel(const float* __restrict__ partial,
                                      const float* __restrict__ rw,
                                      int* __restrict__ e_out) {
  __shared__ float pooled[D_];
  __shared__ float logits[E_];
  int tid = threadIdx.x;
#pragma unroll
  for (int i = 0; i < 3; ++i) {
    int d = tid + i*256;
    float s = 0.f;
    for (int blk = 0; blk < 64; ++blk) s += partial[(size_t)blk*D_ + d];
    pooled[d] = s;  // positive scale factor irrelevant for argmax
  }
  __syncthreads();
  if (tid < E_) {
    float s = 0.f;
    for (int d = 0; d < D_; ++d) s += pooled[d] * rw[d*E_ + tid];
    logits[tid] = s;
  }
  __syncthreads();
  if (tid == 0) {
    int best = 0; float bvv = logits[0];
    for (int e = 1; e < E_; ++e) if (logits[e] > bvv) { bvv = logits[e]; best = e; }
    e_out[0] = best;
  }
}

// ---------------- fp32 -> bf16 convert (n multiple of 2048) ----------------
__global__ void convert_bf16_kernel(const float* __restrict__ src, __bf16* __restrict__ dst) {
  size_t i = ((size_t)blockIdx.x*256 + threadIdx.x)*8;
  __bf16 r[8];
#pragma unroll
  for (int j = 0; j < 8; ++j) r[j] = f2bf(src[i+j]);
  *(bf16x8*)(dst + i) = *(bf16x8*)r;
}

// Wk [L][768][768] fp32 -> rows 768..1535 of wqkv [L][2304][768] bf16
__global__ void convert_wk_kernel(const float* __restrict__ wk, __bf16* __restrict__ wqkv) {
  size_t i = ((size_t)blockIdx.x*256 + threadIdx.x)*8;
  int l = (int)(i / (D_*D_));
  int rem = (int)(i % (D_*D_));
  int n = rem / D_, k = rem % D_;
  __bf16 r[8];
#pragma unroll
  for (int j = 0; j < 8; ++j) r[j] = f2bf(wk[i+j]);
  *(bf16x8*)(wqkv + (size_t)l*2304*D_ + (size_t)(768+n)*D_ + k) = *(bf16x8*)r;
}

// ---------------- TT adapter build: Wq_a / Wv_a -> wqkv bf16 ----------------
__global__ void tt_prep_kernel(
    const float* __restrict__ qc0, const float* __restrict__ qc1, const float* __restrict__ qc2,
    const float* __restrict__ qc3, const float* __restrict__ qc4, const float* __restrict__ qc5,
    const float* __restrict__ vc0, const float* __restrict__ vc1, const float* __restrict__ vc2,
    const float* __restrict__ vc3, const float* __restrict__ vc4, const float* __restrict__ vc5,
    const float* __restrict__ Wq, const float* __restrict__ Wv,
    const int* __restrict__ e_idx, __bf16* __restrict__ wqkv) {
  const int l = blockIdx.x;
  const int pre = blockIdx.y;         // 0 = q, 1 = v
  const int z = blockIdx.z;           // 0..15 -> rows 48z..48z+47
  const int tid = threadIdx.x;
  const int e = e_idx[0];
  const float* c0 = (pre ? vc0 : qc0) + (size_t)(e*L_ + l)*96;   // [12][8]
  const float* c1 = (pre ? vc1 : qc1) + (size_t)(e*L_ + l)*512;  // [8][8][8]
  const float* c2 = (pre ? vc2 : qc2) + (size_t)(e*L_ + l)*512;
  const float* c3 = (pre ? vc3 : qc3) + (size_t)(e*L_ + l)*512;
  const float* c4 = (pre ? vc4 : qc4) + (size_t)(e*L_ + l)*512;
  const float* c5 = (pre ? vc5 : qc5) + (size_t)(e*L_ + l)*96;   // [8][12]
  __shared__ float M1[768];   // [j][l2][m]
  __shared__ float R2[768];   // [q][r][t]
  __shared__ float M2[6144];  // [out][o]
  __shared__ float Rm[6144];  // [o][in]
  for (int idx = tid; idx < 768; idx += 256) {
    int j = idx >> 6, rem = idx & 63, l2 = rem >> 3, m = rem & 7;
    float s = 0.f;
    for (int k = 0; k < 8; ++k) s += c0[j*8 + k] * c1[k*64 + l2*8 + m];
    M1[idx] = s;
    int qq = idx / 96, rem2 = idx % 96, rr = rem2 / 12, t = rem2 % 12;
    float s2 = 0.f;
    for (int si = 0; si < 8; ++si) s2 += c4[qq*64 + rr*8 + si] * c5[si*12 + t];
    R2[idx] = s2;
  }
  __syncthreads();
  for (int idx = tid; idx < 6144; idx += 256) {
    int o = idx & 7, n = (idx >> 3) & 7, jl = idx >> 6;
    float s = 0.f;
    for (int m = 0; m < 8; ++m) s += M1[jl*8 + m] * c2[m*64 + n*8 + o];
    M2[idx] = s;
    int o2 = idx / 768, inp = idx % 768, p = inp / 96, rt = inp % 96;
    float s2 = 0.f;
    for (int qq = 0; qq < 8; ++qq) s2 += c3[o2*64 + p*8 + qq] * R2[qq*96 + rt];
    Rm[idx] = s2;
  }
  __syncthreads();
  const float* Wbase = (pre ? Wv : Wq) + (size_t)l*D_*D_;
  __bf16* dst = wqkv + (size_t)l*2304*D_ + (pre ? (size_t)1536*D_ : 0);
  for (int g = tid; g < 48*96; g += 256) {
    const int outr = z*48 + (g / 96);
    const int inp0 = (g % 96) * 8;
    float m2r[8];
#pragma unroll
    for (int o = 0; o < 8; ++o) m2r[o] = M2[outr*8 + o];
    float acc[8];
#pragma unroll
    for (int u = 0; u < 8; ++u) acc[u] = 0.f;
#pragma unroll
    for (int o = 0; o < 8; ++o) {
      float4 r0 = *(const float4*)&Rm[o*768 + inp0];
      float4 r1 = *(const float4*)&Rm[o*768 + inp0 + 4];
      acc[0] += m2r[o]*r0.x; acc[1] += m2r[o]*r0.y;
      acc[2] += m2r[o]*r0.z; acc[3] += m2r[o]*r0.w;
      acc[4] += m2r[o]*r1.x; acc[5] += m2r[o]*r1.y;
      acc[6] += m2r[o]*r1.z; acc[7] += m2r[o]*r1.w;
    }
    const float* wb = Wbase + (size_t)outr*768 + inp0;
    float4 w0 = *(const float4*)wb;
    float4 w1 = *(const float4*)(wb + 4);
    __bf16 r[8];
    r[0] = f2bf(w0.x + 8.f*acc[0]); r[1] = f2bf(w0.y + 8.f*acc[1]);
    r[2] = f2bf(w0.z + 8.f*acc[2]); r[3] = f2bf(w0.w + 8.f*acc[3]);
    r[4] = f2bf(w1.x + 8.f*acc[4]); r[5] = f2bf(w1.y + 8.f*acc[5]);
    r[6] = f2bf(w1.z + 8.f*acc[6]); r[7] = f2bf(w1.w + 8.f*acc[7]);
    *(bf16x8*)(dst + (size_t)outr*768 + inp0) = *(bf16x8*)r;
  }
}

// ---------------- bf16 MFMA GEMM: C[M][Nw] = A[M][768] * Bw[Nw][768]^T + bias ----------------
// R4-proven 2-D grid (x = N-tiles fastest). All outputs bf16.
// SPLITV path (QKV gemm): blocks x<12 write q/k into outb; x>=12 write V transposed into vt.
// NOTE (R4/R5 A-B): XCD-swizzled 1-D grid cut FETCH 135->75 MB but cost +15% time
// (latency-bound, not fetch-bound) -- keep the natural 2-D order.
template<bool SPLITV>
__global__ __launch_bounds__(256) void gemm_bt(
    const __bf16* __restrict__ A, const __bf16* __restrict__ Bw,
    const float* __restrict__ bq, const float* __restrict__ bk, const float* __restrict__ bvp,
    __bf16* __restrict__ outb, __bf16* __restrict__ vtout, int Nw) {
  const int K = D_;
  __shared__ __align__(16) __bf16 As[128*64];
  __shared__ __align__(16) __bf16 Bs[128*64];
  const int tid = threadIdx.x;
  const int w = tid >> 6, lane = tid & 63;
  const int quad = lane >> 4, l16 = lane & 15;
  const int wr = w >> 1, wc = w & 1;
  const size_t mblk = (size_t)blockIdx.y * 128;
  const size_t nblk = (size_t)blockIdx.x * 128;
  const __bf16* Ab = A + mblk * K;
  const __bf16* Bb = Bw + nblk * K;
  const int lrow = lane >> 3;        // 0..7
  const int scol = (lane & 7) * 8;   // element offset in K
  floatx4 acc[4][4];
#pragma unroll
  for (int i = 0; i < 4; ++i)
#pragma unroll
    for (int j = 0; j < 4; ++j) acc[i][j] = {0.f,0.f,0.f,0.f};

  for (int k0 = 0; k0 < K; k0 += 64) {
    __syncthreads();
#pragma unroll
    for (int i = 0; i < 4; ++i) {
      const int chunk = w*4 + i;           // wave-uniform
      const int row = chunk*8 + lrow;
      async16(Ab + (size_t)row*K + k0 + scol, &As[chunk*512]);
      async16(Bb + (size_t)row*K + k0 + scol, &Bs[chunk*512]);
    }
    __syncthreads();
#pragma unroll
    for (int kk = 0; kk < 64; kk += 32) {
      bf16x8 af[4], bfr[4];
#pragma unroll
      for (int i = 0; i < 4; ++i) af[i]  = *(const bf16x8*)&As[(wr*64 + i*16 + l16)*64 + kk + quad*8];
#pragma unroll
      for (int j = 0; j < 4; ++j) bfr[j] = *(const bf16x8*)&Bs[(wc*64 + j*16 + l16)*64 + kk + quad*8];
#pragma unroll
      for (int i = 0; i < 4; ++i)
#pragma unroll
        for (int j = 0; j < 4; ++j)
          acc[i][j] = __builtin_amdgcn_mfma_f32_16x16x32_bf16(af[i], bfr[j], acc[i][j], 0, 0, 0);
    }
  }
  if (SPLITV && blockIdx.x >= 12) {
    // V block: bias + transpose-write straight into vt[bh][64][512]
#pragma unroll
    for (int j = 0; j < 4; ++j) {
      const int vcol = (int)nblk - 1536 + wc*64 + j*16 + l16;   // 0..767
      const int h = vcol >> 6, d = vcol & 63;
      const float bval = bvp[vcol];
#pragma unroll
      for (int i = 0; i < 4; ++i) {
        const int mrow = (int)mblk + wr*64 + i*16 + quad*4;     // r=0 base
        const int b = mrow >> 9, s = mrow & 511;
        __bf16 pr[4];
#pragma unroll
        for (int r = 0; r < 4; ++r) pr[r] = f2bf(acc[i][j][r] + bval);
        *(bf16x4*)(vtout + (size_t)((b*H_ + h)*64 + d)*S_ + s) = *(bf16x4*)pr;
      }
    }
    return;
  }
  const float* bias = bq;
  if (SPLITV) bias = (blockIdx.x < 6) ? bq : bk;
#pragma unroll
  for (int i = 0; i < 4; ++i) {
#pragma unroll
    for (int j = 0; j < 4; ++j) {
      const int ncol = (int)nblk + wc*64 + j*16 + l16;
      const float bval = bias[ncol % 768];
#pragma unroll
      for (int r = 0; r < 4; ++r) {
        const int mrow = (int)mblk + wr*64 + i*16 + quad*4 + r;
        outb[(size_t)mrow*Nw + ncol] = f2bf(acc[i][j][r] + bval);
      }
    }
  }
}

// ---------------- flash attention v2 (R4-proven): S^T-mfma, padded LDS, XCD swizzle ----------------
// 1-D grid of 3072: n&7 selects XCD-slot; bh = (n>>6)*8 + (n&7); qtile = (n>>3)&7.
#define PSTR 72   // padded LDS row stride (bf16): 144 B -> bank-even b128 access
__global__ __launch_bounds__(256) void flash_kernel(const __bf16* __restrict__ qkv,
                                                    const __bf16* __restrict__ vt,
                                                    __bf16* __restrict__ ctx) {
  __shared__ __align__(16) __bf16 Qs[64*PSTR];    // [q][d]
  __shared__ __align__(16) __bf16 Ks[64*PSTR];    // [kv][d]
  __shared__ __align__(16) __bf16 Vts[64*PSTR];   // [d][kv]
  __shared__ __align__(16) __bf16 Ps[64*PSTR];    // [q][kv], wave w owns rows w*16..+15
  const int tid = threadIdx.x;
  const int w = tid >> 6, lane = tid & 63;
  const int quad = lane >> 4, l16 = lane & 15;
  const int n = blockIdx.x;
  const int bh = (n >> 6)*8 + (n & 7);
  const int q0 = ((n >> 3) & 7) * 64;
  const int b = bh / H_, h = bh % H_;
  const float SCL = 0.125f * 1.44269504f;  // 1/sqrt(64) * log2(e)

  {
#pragma unroll
    for (int it = 0; it < 2; ++it) {
      int slot = it*256 + tid, row = slot >> 3, seg = slot & 7;
      bf16x8 v = *(const bf16x8*)(qkv + (size_t)(b*S_ + q0 + row)*2304 + h*64 + seg*8);
      *(bf16x8*)&Qs[row*PSTR + seg*8] = v;
    }
  }

  floatx4 acc_o[4];   // C[m=q_local=quad*4+r][n=d=jd*16+l16]
#pragma unroll
  for (int jd = 0; jd < 4; ++jd) acc_o[jd] = {0.f,0.f,0.f,0.f};
  float m_prev = -__builtin_inff();   // per-lane q = w*16 + l16 (log2 domain)
  float l_part = 0.f;                 // per-quad partial of the softmax denom

  for (int kt = 0; kt < 8; ++kt) {
    __syncthreads();
#pragma unroll
    for (int it = 0; it < 2; ++it) {
      int slot = it*256 + tid, row = slot >> 3, seg = slot & 7;
      bf16x8 kvv = *(const bf16x8*)(qkv + (size_t)(b*S_ + kt*64 + row)*2304 + 768 + h*64 + seg*8);
      bf16x8 vtv = *(const bf16x8*)(vt + (size_t)(bh*64 + row)*S_ + kt*64 + seg*8);
      *(bf16x8*)&Ks[row*PSTR + seg*8] = kvv;
      *(bf16x8*)&Vts[row*PSTR + seg*8] = vtv;
    }
    __syncthreads();
    // S^T tile: mfma(A=K, B=Q) -> C[m=kv=i*16+quad*4+r][n=q=w*16+l16]
    floatx4 sacc[4];
#pragma unroll
    for (int i = 0; i < 4; ++i) sacc[i] = {0.f,0.f,0.f,0.f};
#pragma unroll
    for (int kk = 0; kk < 64; kk += 32) {
      bf16x8 bq_ = *(const bf16x8*)&Qs[(w*16 + l16)*PSTR + kk + quad*8];
#pragma unroll
      for (int i = 0; i < 4; ++i) {
        bf16x8 ak = *(const bf16x8*)&Ks[(i*16 + l16)*PSTR + kk + quad*8];
        sacc[i] = __builtin_amdgcn_mfma_f32_16x16x32_bf16(ak, bq_, sacc[i], 0, 0, 0);
      }
    }
    float sv[4][4];
#pragma unroll
    for (int i = 0; i < 4; ++i)
#pragma unroll
      for (int r = 0; r < 4; ++r) sv[i][r] = sacc[i][r] * SCL;
    float mloc = sv[0][0];
#pragma unroll
    for (int i = 0; i < 4; ++i)
#pragma unroll
      for (int r = 0; r < 4; ++r) mloc = fmaxf(mloc, sv[i][r]);
    mloc = fmaxf(mloc, __shfl_xor(mloc, 16));
    mloc = fmaxf(mloc, __shfl_xor(mloc, 32));
    float mnew = fmaxf(m_prev, mloc);
    float alpha = fexp2(m_prev - mnew);
    m_prev = mnew;
    float rsum = 0.f;
#pragma unroll
    for (int i = 0; i < 4; ++i) {
      __bf16 pr[4];
#pragma unroll
      for (int r = 0; r < 4; ++r) {
        float p = fexp2(sv[i][r] - mnew);
        rsum += p;
        pr[r] = f2bf(p);
      }
      *(bf16x4*)&Ps[(w*16 + l16)*PSTR + i*16 + quad*4] = *(bf16x4*)pr;  // b64, bank-even
    }
    l_part = l_part*alpha + rsum;
    float ab[4];
#pragma unroll
    for (int r = 0; r < 4; ++r) ab[r] = __shfl(alpha, quad*4 + r);
#pragma unroll
    for (int jd = 0; jd < 4; ++jd)
#pragma unroll
      for (int r = 0; r < 4; ++r) acc_o[jd][r] *= ab[r];
    // O += P V : same-wave ds write->read is in-order
#pragma unroll
    for (int kk = 0; kk < 64; kk += 32) {
      bf16x8 ap = *(const bf16x8*)&Ps[(w*16 + l16)*PSTR + kk + quad*8];
#pragma unroll
      for (int jd = 0; jd < 4; ++jd) {
        bf16x8 bv_ = *(const bf16x8*)&Vts[(jd*16 + l16)*PSTR + kk + quad*8];
        acc_o[jd] = __builtin_amdgcn_mfma_f32_16x16x32_bf16(ap, bv_, acc_o[jd], 0, 0, 0);
      }
    }
  }
  float l_tot = l_part;
  l_tot += __shfl_xor(l_tot, 16);
  l_tot += __shfl_xor(l_tot, 32);
  float lb[4];
#pragma unroll
  for (int r = 0; r < 4; ++r) lb[r] = __shfl(l_tot, quad*4 + r);
#pragma unroll
  for (int jd = 0; jd < 4; ++jd) {
    const int d = jd*16 + l16;
#pragma unroll
    for (int r = 0; r < 4; ++r) {
      const int q = q0 + w*16 + quad*4 + r;
      ctx[(size_t)(b*S_ + q)*D_ + h*64 + d] = f2bf(acc_o[jd][r] / lb[r]);
    }
  }
}

// ---------------- residual + LayerNorm (fp32 stats), proj read as bf16 ----------------
__global__ __launch_bounds__(256) void ln_kernel(const float* __restrict__ resid,
                                                 const __bf16* __restrict__ proj,
                                                 const float* __restrict__ gamma,
                                                 const float* __restrict__ beta,
                                                 float* __restrict__ xout,
                                                 __bf16* __restrict__ xbf) {
  const int row = blockIdx.x;
  const int tid = threadIdx.x;
  const int w = tid >> 6, lane = tid & 63;
  __shared__ float red[4];
  float v[3]; int dd[3];
#pragma unroll
  for (int i = 0; i < 3; ++i) {
    int d = tid + i*256; dd[i] = d;
    v[i] = resid[(size_t)row*D_ + d] + (float)proj[(size_t)row*D_ + d];
  }
  float s = v[0] + v[1] + v[2];
#pragma unroll
  for (int off = 32; off; off >>= 1) s += __shfl_xor(s, off);
  if (lane == 0) red[w] = s;
  __syncthreads();
  float mu = (red[0]+red[1]+red[2]+red[3]) * (1.f/768.f);
  __syncthreads();
  float q = 0.f;
#pragma unroll
  for (int i = 0; i < 3; ++i) { float d = v[i]-mu; q += d*d; }
#pragma unroll
  for (int off = 32; off; off >>= 1) q += __shfl_xor(q, off);
  if (lane == 0) red[w] = q;
  __syncthreads();
  float var = (red[0]+red[1]+red[2]+red[3]) * (1.f/768.f);
  float rs = rsqrtf(var + 1e-12f);
#pragma unroll
  for (int i = 0; i < 3; ++i) {
    float o = (v[i]-mu)*rs*gamma[dd[i]] + beta[dd[i]];
    xout[(size_t)row*D_ + dd[i]] = o;
    xbf[(size_t)row*D_ + dd[i]] = f2bf(o);
  }
}

extern "C" void kernel_launch(void* const* d_in, const int* in_sizes, int n_in,
                              void* d_out, int out_size, void* d_ws, size_t ws_size,
                              hipStream_t stream) {
  const float* hidden = (const float*)d_in[0];
  const float* router = (const float*)d_in[1];
  const float* qc[6]; const float* vc[6];
  for (int i = 0; i < 6; ++i) qc[i] = (const float*)d_in[2+i];
  for (int i = 0; i < 6; ++i) vc[i] = (const float*)d_in[8+i];
  const float* Wq = (const float*)d_in[14];
  const float* Wk = (const float*)d_in[15];
  const float* Wv = (const float*)d_in[16];
  const float* Wo = (const float*)d_in[17];
  const float* bq = (const float*)d_in[18];
  const float* bk = (const float*)d_in[19];
  const float* bv = (const float*)d_in[20];
  const float* bo = (const float*)d_in[21];
  const float* lns = (const float*)d_in[22];
  const float* lnb = (const float*)d_in[23];
  float* out = (float*)d_out;

  char* ws = (char*)d_ws;
  size_t off = 0;
  auto alloc = [&](size_t bytes) -> void* {
    off = (off + 255) & ~(size_t)255;
    void* p = ws + off; off += bytes; return p;
  };
  int*    e_idx = (int*)   alloc(4);
  float*  rpart = (float*) alloc((size_t)64*D_*4);
  __bf16* xbf   = (__bf16*)alloc((size_t)BS_*D_*2);
  __bf16* qkv   = (__bf16*)alloc((size_t)BS_*2304*2);
  __bf16* vt    = (__bf16*)alloc((size_t)B_*H_*64*S_*2);
  __bf16* ctx   = (__bf16*)alloc((size_t)BS_*D_*2);
  __bf16* projb = (__bf16*)alloc((size_t)BS_*D_*2);
  __bf16* wqkv  = (__bf16*)alloc((size_t)L_*2304*D_*2);
  __bf16* wobf  = (__bf16*)alloc((size_t)L_*D_*D_*2);
  (void)ws_size; (void)in_sizes; (void)n_in; (void)out_size;

  routing_pool_kernel<<<64, 256, 0, stream>>>(hidden, rpart);
  routing_finish_kernel<<<1, 256, 0, stream>>>(rpart, router, e_idx);
  convert_bf16_kernel<<<(BS_*D_)/2048, 256, 0, stream>>>(hidden, xbf);
  tt_prep_kernel<<<dim3(L_, 2, 16), 256, 0, stream>>>(qc[0],qc[1],qc[2],qc[3],qc[4],qc[5],
                                                      vc[0],vc[1],vc[2],vc[3],vc[4],vc[5],
                                                      Wq, Wv, e_idx, wqkv);
  convert_wk_kernel<<<(L_*D_*D_)/2048, 256, 0, stream>>>(Wk, wqkv);
  convert_bf16_kernel<<<(L_*D_*D_)/2048, 256, 0, stream>>>(Wo, wobf);

  for (int l = 0; l < L_; ++l) {
    gemm_bt<true><<<dim3(18,128), 256, 0, stream>>>(xbf, wqkv + (size_t)l*2304*D_,
        bq + l*D_, bk + l*D_, bv + l*D_, qkv, vt, 2304);
    flash_kernel<<<3072, 256, 0, stream>>>(qkv, vt, ctx);
    gemm_bt<false><<<dim3(6,128), 256, 0, stream>>>(ctx, wobf + (size_t)l*D_*D_,
        bo + l*D_, nullptr, nullptr, projb, nullptr, 768);
    ln_kernel<<<BS_, 256, 0, stream>>>(l == 0 ? hidden : out, projb,
        lns + l*D_, lnb + l*D_, out, xbf);
  }
}

// Round 7
// 2926.474 us; speedup vs baseline: 1.1450x; 1.0425x over previous
//
#include <hip/hip_runtime.h>
#include <hip/hip_bf16.h>
#include <stdint.h>

#define E_ 8
#define L_ 12
#define D_ 768
#define H_ 12
#define S_ 512
#define B_ 32
#define BS_ (B_*S_)   // 16384

typedef __attribute__((ext_vector_type(4))) float floatx4;
typedef __attribute__((ext_vector_type(8))) __bf16 bf16x8;
typedef __attribute__((ext_vector_type(4))) __bf16 bf16x4;

__device__ __forceinline__ __bf16 f2bf(float f) {
  unsigned u = __builtin_bit_cast(unsigned, f);
  u += 0x7fffu + ((u >> 16) & 1u);           // RNE
  unsigned short h = (unsigned short)(u >> 16);
  return __builtin_bit_cast(__bf16, h);
}

__device__ __forceinline__ float fexp2(float x) {
#if __has_builtin(__builtin_amdgcn_exp2f)
  return __builtin_amdgcn_exp2f(x);
#else
  return exp2f(x);
#endif
}

__device__ __forceinline__ void async16(const void* g, void* l) {
  __builtin_amdgcn_global_load_lds((__attribute__((address_space(1))) void*)g,
                                   (__attribute__((address_space(3))) void*)l,
                                   16, 0, 0);
}

// ---------------- routing stage 1: 64 blocks x 8 rows, coalesced partial sums ----------------
__global__ void routing_pool_kernel(const float* __restrict__ hidden,
                                    float* __restrict__ partial) {
  const int blk = blockIdx.x;    // 0..63
  const int tid = threadIdx.x;
  const float* base = hidden + (size_t)(B_-1)*S_*D_ + (size_t)blk*8*D_;
  float acc[3] = {0.f, 0.f, 0.f};
  for (int s = 0; s < 8; ++s) {
#pragma unroll
    for (int i = 0; i < 3; ++i)
      acc[i] += base[(size_t)s*D_ + tid + i*256];
  }
#pragma unroll
  for (int i = 0; i < 3; ++i) partial[(size_t)blk*D_ + tid + i*256] = acc[i];
}

// ---------------- routing stage 2: reduce partials, logits, argmax ----------------
__global__ void routing_finish_kernel(const float* __restrict__ partial,
                                      const float* __restrict__ rw,
                                      int* __restrict__ e_out) {
  __shared__ float pooled[D_];
  __shared__ float logits[E_];
  int tid = threadIdx.x;
#pragma unroll
  for (int i = 0; i < 3; ++i) {
    int d = tid + i*256;
    float s = 0.f;
    for (int blk = 0; blk < 64; ++blk) s += partial[(size_t)blk*D_ + d];
    pooled[d] = s;  // positive scale factor irrelevant for argmax
  }
  __syncthreads();
  if (tid < E_) {
    float s = 0.f;
    for (int d = 0; d < D_; ++d) s += pooled[d] * rw[d*E_ + tid];
    logits[tid] = s;
  }
  __syncthreads();
  if (tid == 0) {
    int best = 0; float bvv = logits[0];
    for (int e = 1; e < E_; ++e) if (logits[e] > bvv) { bvv = logits[e]; best = e; }
    e_out[0] = best;
  }
}

// ---------------- fp32 -> bf16 convert (n multiple of 2048) ----------------
__global__ void convert_bf16_kernel(const float* __restrict__ src, __bf16* __restrict__ dst) {
  size_t i = ((size_t)blockIdx.x*256 + threadIdx.x)*8;
  __bf16 r[8];
#pragma unroll
  for (int j = 0; j < 8; ++j) r[j] = f2bf(src[i+j]);
  *(bf16x8*)(dst + i) = *(bf16x8*)r;
}

// Wk [L][768][768] fp32 -> rows 768..1535 of wqkv [L][2304][768] bf16
__global__ void convert_wk_kernel(const float* __restrict__ wk, __bf16* __restrict__ wqkv) {
  size_t i = ((size_t)blockIdx.x*256 + threadIdx.x)*8;
  int l = (int)(i / (D_*D_));
  int rem = (int)(i % (D_*D_));
  int n = rem / D_, k = rem % D_;
  __bf16 r[8];
#pragma unroll
  for (int j = 0; j < 8; ++j) r[j] = f2bf(wk[i+j]);
  *(bf16x8*)(wqkv + (size_t)l*2304*D_ + (size_t)(768+n)*D_ + k) = *(bf16x8*)r;
}

// ---------------- TT adapter build: Wq_a / Wv_a -> wqkv bf16 ----------------
__global__ void tt_prep_kernel(
    const float* __restrict__ qc0, const float* __restrict__ qc1, const float* __restrict__ qc2,
    const float* __restrict__ qc3, const float* __restrict__ qc4, const float* __restrict__ qc5,
    const float* __restrict__ vc0, const float* __restrict__ vc1, const float* __restrict__ vc2,
    const float* __restrict__ vc3, const float* __restrict__ vc4, const float* __restrict__ vc5,
    const float* __restrict__ Wq, const float* __restrict__ Wv,
    const int* __restrict__ e_idx, __bf16* __restrict__ wqkv) {
  const int l = blockIdx.x;
  const int pre = blockIdx.y;         // 0 = q, 1 = v
  const int z = blockIdx.z;           // 0..15 -> rows 48z..48z+47
  const int tid = threadIdx.x;
  const int e = e_idx[0];
  const float* c0 = (pre ? vc0 : qc0) + (size_t)(e*L_ + l)*96;   // [12][8]
  const float* c1 = (pre ? vc1 : qc1) + (size_t)(e*L_ + l)*512;  // [8][8][8]
  const float* c2 = (pre ? vc2 : qc2) + (size_t)(e*L_ + l)*512;
  const float* c3 = (pre ? vc3 : qc3) + (size_t)(e*L_ + l)*512;
  const float* c4 = (pre ? vc4 : qc4) + (size_t)(e*L_ + l)*512;
  const float* c5 = (pre ? vc5 : qc5) + (size_t)(e*L_ + l)*96;   // [8][12]
  __shared__ float M1[768];   // [j][l2][m]
  __shared__ float R2[768];   // [q][r][t]
  __shared__ float M2[6144];  // [out][o]
  __shared__ float Rm[6144];  // [o][in]
  for (int idx = tid; idx < 768; idx += 256) {
    int j = idx >> 6, rem = idx & 63, l2 = rem >> 3, m = rem & 7;
    float s = 0.f;
    for (int k = 0; k < 8; ++k) s += c0[j*8 + k] * c1[k*64 + l2*8 + m];
    M1[idx] = s;
    int qq = idx / 96, rem2 = idx % 96, rr = rem2 / 12, t = rem2 % 12;
    float s2 = 0.f;
    for (int si = 0; si < 8; ++si) s2 += c4[qq*64 + rr*8 + si] * c5[si*12 + t];
    R2[idx] = s2;
  }
  __syncthreads();
  for (int idx = tid; idx < 6144; idx += 256) {
    int o = idx & 7, n = (idx >> 3) & 7, jl = idx >> 6;
    float s = 0.f;
    for (int m = 0; m < 8; ++m) s += M1[jl*8 + m] * c2[m*64 + n*8 + o];
    M2[idx] = s;
    int o2 = idx / 768, inp = idx % 768, p = inp / 96, rt = inp % 96;
    float s2 = 0.f;
    for (int qq = 0; qq < 8; ++qq) s2 += c3[o2*64 + p*8 + qq] * R2[qq*96 + rt];
    Rm[idx] = s2;
  }
  __syncthreads();
  const float* Wbase = (pre ? Wv : Wq) + (size_t)l*D_*D_;
  __bf16* dst = wqkv + (size_t)l*2304*D_ + (pre ? (size_t)1536*D_ : 0);
  for (int g = tid; g < 48*96; g += 256) {
    const int outr = z*48 + (g / 96);
    const int inp0 = (g % 96) * 8;
    float m2r[8];
#pragma unroll
    for (int o = 0; o < 8; ++o) m2r[o] = M2[outr*8 + o];
    float acc[8];
#pragma unroll
    for (int u = 0; u < 8; ++u) acc[u] = 0.f;
#pragma unroll
    for (int o = 0; o < 8; ++o) {
      float4 r0 = *(const float4*)&Rm[o*768 + inp0];
      float4 r1 = *(const float4*)&Rm[o*768 + inp0 + 4];
      acc[0] += m2r[o]*r0.x; acc[1] += m2r[o]*r0.y;
      acc[2] += m2r[o]*r0.z; acc[3] += m2r[o]*r0.w;
      acc[4] += m2r[o]*r1.x; acc[5] += m2r[o]*r1.y;
      acc[6] += m2r[o]*r1.z; acc[7] += m2r[o]*r1.w;
    }
    const float* wb = Wbase + (size_t)outr*768 + inp0;
    float4 w0 = *(const float4*)wb;
    float4 w1 = *(const float4*)(wb + 4);
    __bf16 r[8];
    r[0] = f2bf(w0.x + 8.f*acc[0]); r[1] = f2bf(w0.y + 8.f*acc[1]);
    r[2] = f2bf(w0.z + 8.f*acc[2]); r[3] = f2bf(w0.w + 8.f*acc[3]);
    r[4] = f2bf(w1.x + 8.f*acc[4]); r[5] = f2bf(w1.y + 8.f*acc[5]);
    r[6] = f2bf(w1.z + 8.f*acc[6]); r[7] = f2bf(w1.w + 8.f*acc[7]);
    *(bf16x8*)(dst + (size_t)outr*768 + inp0) = *(bf16x8*)r;
  }
}

// ---------------- bf16 MFMA GEMM: C[M][Nw] = A[M][768] * Bw[Nw][768]^T + bias ----------------
// R4-proven 2-D grid (x = N-tiles fastest). All outputs bf16.
// SPLITV path (QKV gemm): blocks x<12 write q/k into outb; x>=12 write V transposed into vt.
// NOTE (R4/R5 A-B): XCD-swizzled 1-D grid cut FETCH 135->75 MB but cost +15% time
// (latency-bound, not fetch-bound) -- keep the natural 2-D order.
template<bool SPLITV>
__global__ __launch_bounds__(256) void gemm_bt(
    const __bf16* __restrict__ A, const __bf16* __restrict__ Bw,
    const float* __restrict__ bq, const float* __restrict__ bk, const float* __restrict__ bvp,
    __bf16* __restrict__ outb, __bf16* __restrict__ vtout, int Nw) {
  const int K = D_;
  __shared__ __align__(16) __bf16 As[128*64];
  __shared__ __align__(16) __bf16 Bs[128*64];
  const int tid = threadIdx.x;
  const int w = tid >> 6, lane = tid & 63;
  const int quad = lane >> 4, l16 = lane & 15;
  const int wr = w >> 1, wc = w & 1;
  const size_t mblk = (size_t)blockIdx.y * 128;
  const size_t nblk = (size_t)blockIdx.x * 128;
  const __bf16* Ab = A + mblk * K;
  const __bf16* Bb = Bw + nblk * K;
  const int lrow = lane >> 3;        // 0..7
  const int scol = (lane & 7) * 8;   // element offset in K
  floatx4 acc[4][4];
#pragma unroll
  for (int i = 0; i < 4; ++i)
#pragma unroll
    for (int j = 0; j < 4; ++j) acc[i][j] = {0.f,0.f,0.f,0.f};

  for (int k0 = 0; k0 < K; k0 += 64) {
    __syncthreads();
#pragma unroll
    for (int i = 0; i < 4; ++i) {
      const int chunk = w*4 + i;           // wave-uniform
      const int row = chunk*8 + lrow;
      async16(Ab + (size_t)row*K + k0 + scol, &As[chunk*512]);
      async16(Bb + (size_t)row*K + k0 + scol, &Bs[chunk*512]);
    }
    __syncthreads();
#pragma unroll
    for (int kk = 0; kk < 64; kk += 32) {
      bf16x8 af[4], bfr[4];
#pragma unroll
      for (int i = 0; i < 4; ++i) af[i]  = *(const bf16x8*)&As[(wr*64 + i*16 + l16)*64 + kk + quad*8];
#pragma unroll
      for (int j = 0; j < 4; ++j) bfr[j] = *(const bf16x8*)&Bs[(wc*64 + j*16 + l16)*64 + kk + quad*8];
#pragma unroll
      for (int i = 0; i < 4; ++i)
#pragma unroll
        for (int j = 0; j < 4; ++j)
          acc[i][j] = __builtin_amdgcn_mfma_f32_16x16x32_bf16(af[i], bfr[j], acc[i][j], 0, 0, 0);
    }
  }
  if (SPLITV && blockIdx.x >= 12) {
    // V block: bias + transpose-write straight into vt[bh][64][512]
#pragma unroll
    for (int j = 0; j < 4; ++j) {
      const int vcol = (int)nblk - 1536 + wc*64 + j*16 + l16;   // 0..767
      const int h = vcol >> 6, d = vcol & 63;
      const float bval = bvp[vcol];
#pragma unroll
      for (int i = 0; i < 4; ++i) {
        const int mrow = (int)mblk + wr*64 + i*16 + quad*4;     // r=0 base
        const int b = mrow >> 9, s = mrow & 511;
        __bf16 pr[4];
#pragma unroll
        for (int r = 0; r < 4; ++r) pr[r] = f2bf(acc[i][j][r] + bval);
        *(bf16x4*)(vtout + (size_t)((b*H_ + h)*64 + d)*S_ + s) = *(bf16x4*)pr;
      }
    }
    return;
  }
  const float* bias = bq;
  if (SPLITV) bias = (blockIdx.x < 6) ? bq : bk;
#pragma unroll
  for (int i = 0; i < 4; ++i) {
#pragma unroll
    for (int j = 0; j < 4; ++j) {
      const int ncol = (int)nblk + wc*64 + j*16 + l16;
      const float bval = bias[ncol % 768];
#pragma unroll
      for (int r = 0; r < 4; ++r) {
        const int mrow = (int)mblk + wr*64 + i*16 + quad*4 + r;
        outb[(size_t)mrow*Nw + ncol] = f2bf(acc[i][j][r] + bval);
      }
    }
  }
}

// ---------------- flash attention v2 (R4-proven): S^T-mfma, padded LDS, XCD swizzle ----------------
// 1-D grid of 3072: n&7 selects XCD-slot; bh = (n>>6)*8 + (n&7); qtile = (n>>3)&7.
#define PSTR 72   // padded LDS row stride (bf16): 144 B -> bank-even b128 access
__global__ __launch_bounds__(256) void flash_kernel(const __bf16* __restrict__ qkv,
                                                    const __bf16* __restrict__ vt,
                                                    __bf16* __restrict__ ctx) {
  __shared__ __align__(16) __bf16 Qs[64*PSTR];    // [q][d]
  __shared__ __align__(16) __bf16 Ks[64*PSTR];    // [kv][d]
  __shared__ __align__(16) __bf16 Vts[64*PSTR];   // [d][kv]
  __shared__ __align__(16) __bf16 Ps[64*PSTR];    // [q][kv], wave w owns rows w*16..+15
  const int tid = threadIdx.x;
  const int w = tid >> 6, lane = tid & 63;
  const int quad = lane >> 4, l16 = lane & 15;
  const int n = blockIdx.x;
  const int bh = (n >> 6)*8 + (n & 7);
  const int q0 = ((n >> 3) & 7) * 64;
  const int b = bh / H_, h = bh % H_;
  const float SCL = 0.125f * 1.44269504f;  // 1/sqrt(64) * log2(e)

  {
#pragma unroll
    for (int it = 0; it < 2; ++it) {
      int slot = it*256 + tid, row = slot >> 3, seg = slot & 7;
      bf16x8 v = *(const bf16x8*)(qkv + (size_t)(b*S_ + q0 + row)*2304 + h*64 + seg*8);
      *(bf16x8*)&Qs[row*PSTR + seg*8] = v;
    }
  }

  floatx4 acc_o[4];   // C[m=q_local=quad*4+r][n=d=jd*16+l16]
#pragma unroll
  for (int jd = 0; jd < 4; ++jd) acc_o[jd] = {0.f,0.f,0.f,0.f};
  float m_prev = -__builtin_inff();   // per-lane q = w*16 + l16 (log2 domain)
  float l_part = 0.f;                 // per-quad partial of the softmax denom

  for (int kt = 0; kt < 8; ++kt) {
    __syncthreads();
#pragma unroll
    for (int it = 0; it < 2; ++it) {
      int slot = it*256 + tid, row = slot >> 3, seg = slot & 7;
      bf16x8 kvv = *(const bf16x8*)(qkv + (size_t)(b*S_ + kt*64 + row)*2304 + 768 + h*64 + seg*8);
      bf16x8 vtv = *(const bf16x8*)(vt + (size_t)(bh*64 + row)*S_ + kt*64 + seg*8);
      *(bf16x8*)&Ks[row*PSTR + seg*8] = kvv;
      *(bf16x8*)&Vts[row*PSTR + seg*8] = vtv;
    }
    __syncthreads();
    // S^T tile: mfma(A=K, B=Q) -> C[m=kv=i*16+quad*4+r][n=q=w*16+l16]
    floatx4 sacc[4];
#pragma unroll
    for (int i = 0; i < 4; ++i) sacc[i] = {0.f,0.f,0.f,0.f};
#pragma unroll
    for (int kk = 0; kk < 64; kk += 32) {
      bf16x8 bq_ = *(const bf16x8*)&Qs[(w*16 + l16)*PSTR + kk + quad*8];
#pragma unroll
      for (int i = 0; i < 4; ++i) {
        bf16x8 ak = *(const bf16x8*)&Ks[(i*16 + l16)*PSTR + kk + quad*8];
        sacc[i] = __builtin_amdgcn_mfma_f32_16x16x32_bf16(ak, bq_, sacc[i], 0, 0, 0);
      }
    }
    float sv[4][4];
#pragma unroll
    for (int i = 0; i < 4; ++i)
#pragma unroll
      for (int r = 0; r < 4; ++r) sv[i][r] = sacc[i][r] * SCL;
    float mloc = sv[0][0];
#pragma unroll
    for (int i = 0; i < 4; ++i)
#pragma unroll
      for (int r = 0; r < 4; ++r) mloc = fmaxf(mloc, sv[i][r]);
    mloc = fmaxf(mloc, __shfl_xor(mloc, 16));
    mloc = fmaxf(mloc, __shfl_xor(mloc, 32));
    float mnew = fmaxf(m_prev, mloc);
    float alpha = fexp2(m_prev - mnew);
    m_prev = mnew;
    float rsum = 0.f;
#pragma unroll
    for (int i = 0; i < 4; ++i) {
      __bf16 pr[4];
#pragma unroll
      for (int r = 0; r < 4; ++r) {
        float p = fexp2(sv[i][r] - mnew);
        rsum += p;
        pr[r] = f2bf(p);
      }
      *(bf16x4*)&Ps[(w*16 + l16)*PSTR + i*16 + quad*4] = *(bf16x4*)pr;  // b64, bank-even
    }
    l_part = l_part*alpha + rsum;
    float ab[4];
#pragma unroll
    for (int r = 0; r < 4; ++r) ab[r] = __shfl(alpha, quad*4 + r);
#pragma unroll
    for (int jd = 0; jd < 4; ++jd)
#pragma unroll
      for (int r = 0; r < 4; ++r) acc_o[jd][r] *= ab[r];
    // O += P V : same-wave ds write->read is in-order
#pragma unroll
    for (int kk = 0; kk < 64; kk += 32) {
      bf16x8 ap = *(const bf16x8*)&Ps[(w*16 + l16)*PSTR + kk + quad*8];
#pragma unroll
      for (int jd = 0; jd < 4; ++jd) {
        bf16x8 bv_ = *(const bf16x8*)&Vts[(jd*16 + l16)*PSTR + kk + quad*8];
        acc_o[jd] = __builtin_amdgcn_mfma_f32_16x16x32_bf16(ap, bv_, acc_o[jd], 0, 0, 0);
      }
    }
  }
  float l_tot = l_part;
  l_tot += __shfl_xor(l_tot, 16);
  l_tot += __shfl_xor(l_tot, 32);
  float lb[4];
#pragma unroll
  for (int r = 0; r < 4; ++r) lb[r] = __shfl(l_tot, quad*4 + r);
#pragma unroll
  for (int jd = 0; jd < 4; ++jd) {
    const int d = jd*16 + l16;
#pragma unroll
    for (int r = 0; r < 4; ++r) {
      const int q = q0 + w*16 + quad*4 + r;
      ctx[(size_t)(b*S_ + q)*D_ + h*64 + d] = f2bf(acc_o[jd][r] / lb[r]);
    }
  }
}

// ---------------- residual + LayerNorm v2: wave-per-row, bf16 master chain ----------------
// 4 rows/block (one wave each), bf16x8 loads, shuffle-only reduction (no LDS/barrier).
// Lane covers cols lane*8..+7 (all lanes) and 512+lane*8..+7 (lanes<32).
// FIRST: residual read from fp32 hidden. LAST: write fp32 to d_out; else bf16 in-place xb.
template<bool FIRST, bool LAST>
__global__ __launch_bounds__(256) void ln_kernel(const float* __restrict__ residf,
                                                 __bf16* xb,           // resid in (l>0) + out (l<11); in-place
                                                 const __bf16* __restrict__ proj,
                                                 const float* __restrict__ gamma,
                                                 const float* __restrict__ beta,
                                                 float* __restrict__ xoutf) {
  const int tid = threadIdx.x;
  const int w = tid >> 6, lane = tid & 63;
  const int row = blockIdx.x*4 + w;
  const size_t base = (size_t)row * D_;
  const int c0 = lane*8;
  const bool has2 = lane < 32;
  const int c1 = 512 + lane*8;

  float v0[8], v1[8];
  {
    bf16x8 p0 = *(const bf16x8*)(proj + base + c0);
    if (FIRST) {
      float4 a = *(const float4*)(residf + base + c0);
      float4 bq4 = *(const float4*)(residf + base + c0 + 4);
      v0[0]=a.x+(float)p0[0]; v0[1]=a.y+(float)p0[1]; v0[2]=a.z+(float)p0[2]; v0[3]=a.w+(float)p0[3];
      v0[4]=bq4.x+(float)p0[4]; v0[5]=bq4.y+(float)p0[5]; v0[6]=bq4.z+(float)p0[6]; v0[7]=bq4.w+(float)p0[7];
    } else {
      bf16x8 r0 = *(const bf16x8*)(xb + base + c0);
#pragma unroll
      for (int j = 0; j < 8; ++j) v0[j] = (float)r0[j] + (float)p0[j];
    }
    if (has2) {
      bf16x8 p1 = *(const bf16x8*)(proj + base + c1);
      if (FIRST) {
        float4 a = *(const float4*)(residf + base + c1);
        float4 bq4 = *(const float4*)(residf + base + c1 + 4);
        v1[0]=a.x+(float)p1[0]; v1[1]=a.y+(float)p1[1]; v1[2]=a.z+(float)p1[2]; v1[3]=a.w+(float)p1[3];
        v1[4]=bq4.x+(float)p1[4]; v1[5]=bq4.y+(float)p1[5]; v1[6]=bq4.z+(float)p1[6]; v1[7]=bq4.w+(float)p1[7];
      } else {
        bf16x8 r1 = *(const bf16x8*)(xb + base + c1);
#pragma unroll
        for (int j = 0; j < 8; ++j) v1[j] = (float)r1[j] + (float)p1[j];
      }
    } else {
#pragma unroll
      for (int j = 0; j < 8; ++j) v1[j] = 0.f;
    }
  }
  float s = 0.f;
#pragma unroll
  for (int j = 0; j < 8; ++j) s += v0[j] + v1[j];
#pragma unroll
  for (int off = 32; off; off >>= 1) s += __shfl_xor(s, off);
  const float mu = s * (1.f/768.f);
  float q = 0.f;
#pragma unroll
  for (int j = 0; j < 8; ++j) { float d0 = v0[j]-mu; q += d0*d0; }
  if (has2) {
#pragma unroll
    for (int j = 0; j < 8; ++j) { float d1 = v1[j]-mu; q += d1*d1; }
  }
#pragma unroll
  for (int off = 32; off; off >>= 1) q += __shfl_xor(q, off);
  const float rs = rsqrtf(q * (1.f/768.f) + 1e-12f);

  {
    float4 g0 = *(const float4*)(gamma + c0);
    float4 g1 = *(const float4*)(gamma + c0 + 4);
    float4 b0 = *(const float4*)(beta + c0);
    float4 b1 = *(const float4*)(beta + c0 + 4);
    float o[8];
    o[0]=(v0[0]-mu)*rs*g0.x+b0.x; o[1]=(v0[1]-mu)*rs*g0.y+b0.y;
    o[2]=(v0[2]-mu)*rs*g0.z+b0.z; o[3]=(v0[3]-mu)*rs*g0.w+b0.w;
    o[4]=(v0[4]-mu)*rs*g1.x+b1.x; o[5]=(v0[5]-mu)*rs*g1.y+b1.y;
    o[6]=(v0[6]-mu)*rs*g1.z+b1.z; o[7]=(v0[7]-mu)*rs*g1.w+b1.w;
    if (LAST) {
      *(float4*)(xoutf + base + c0)     = {o[0],o[1],o[2],o[3]};
      *(float4*)(xoutf + base + c0 + 4) = {o[4],o[5],o[6],o[7]};
    } else {
      __bf16 ob[8];
#pragma unroll
      for (int j = 0; j < 8; ++j) ob[j] = f2bf(o[j]);
      *(bf16x8*)(xb + base + c0) = *(bf16x8*)ob;
    }
  }
  if (has2) {
    float4 g0 = *(const float4*)(gamma + c1);
    float4 g1 = *(const float4*)(gamma + c1 + 4);
    float4 b0 = *(const float4*)(beta + c1);
    float4 b1 = *(const float4*)(beta + c1 + 4);
    float o[8];
    o[0]=(v1[0]-mu)*rs*g0.x+b0.x; o[1]=(v1[1]-mu)*rs*g0.y+b0.y;
    o[2]=(v1[2]-mu)*rs*g0.z+b0.z; o[3]=(v1[3]-mu)*rs*g0.w+b0.w;
    o[4]=(v1[4]-mu)*rs*g1.x+b1.x; o[5]=(v1[5]-mu)*rs*g1.y+b1.y;
    o[6]=(v1[6]-mu)*rs*g1.z+b1.z; o[7]=(v1[7]-mu)*rs*g1.w+b1.w;
    if (LAST) {
      *(float4*)(xoutf + base + c1)     = {o[0],o[1],o[2],o[3]};
      *(float4*)(xoutf + base + c1 + 4) = {o[4],o[5],o[6],o[7]};
    } else {
      __bf16 ob[8];
#pragma unroll
      for (int j = 0; j < 8; ++j) ob[j] = f2bf(o[j]);
      *(bf16x8*)(xb + base + c1) = *(bf16x8*)ob;
    }
  }
}

extern "C" void kernel_launch(void* const* d_in, const int* in_sizes, int n_in,
                              void* d_out, int out_size, void* d_ws, size_t ws_size,
                              hipStream_t stream) {
  const float* hidden = (const float*)d_in[0];
  const float* router = (const float*)d_in[1];
  const float* qc[6]; const float* vc[6];
  for (int i = 0; i < 6; ++i) qc[i] = (const float*)d_in[2+i];
  for (int i = 0; i < 6; ++i) vc[i] = (const float*)d_in[8+i];
  const float* Wq = (const float*)d_in[14];
  const float* Wk = (const float*)d_in[15];
  const float* Wv = (const float*)d_in[16];
  const float* Wo = (const float*)d_in[17];
  const float* bq = (const float*)d_in[18];
  const float* bk = (const float*)d_in[19];
  const float* bv = (const float*)d_in[20];
  const float* bo = (const float*)d_in[21];
  const float* lns = (const float*)d_in[22];
  const float* lnb = (const float*)d_in[23];
  float* out = (float*)d_out;

  char* ws = (char*)d_ws;
  size_t off = 0;
  auto alloc = [&](size_t bytes) -> void* {
    off = (off + 255) & ~(size_t)255;
    void* p = ws + off; off += bytes; return p;
  };
  int*    e_idx = (int*)   alloc(4);
  float*  rpart = (float*) alloc((size_t)64*D_*4);
  __bf16* xbf   = (__bf16*)alloc((size_t)BS_*D_*2);
  __bf16* qkv   = (__bf16*)alloc((size_t)BS_*2304*2);
  __bf16* vt    = (__bf16*)alloc((size_t)B_*H_*64*S_*2);
  __bf16* ctx   = (__bf16*)alloc((size_t)BS_*D_*2);
  __bf16* projb = (__bf16*)alloc((size_t)BS_*D_*2);
  __bf16* wqkv  = (__bf16*)alloc((size_t)L_*2304*D_*2);
  __bf16* wobf  = (__bf16*)alloc((size_t)L_*D_*D_*2);
  (void)ws_size; (void)in_sizes; (void)n_in; (void)out_size;

  routing_pool_kernel<<<64, 256, 0, stream>>>(hidden, rpart);
  routing_finish_kernel<<<1, 256, 0, stream>>>(rpart, router, e_idx);
  convert_bf16_kernel<<<(BS_*D_)/2048, 256, 0, stream>>>(hidden, xbf);
  tt_prep_kernel<<<dim3(L_, 2, 16), 256, 0, stream>>>(qc[0],qc[1],qc[2],qc[3],qc[4],qc[5],
                                                      vc[0],vc[1],vc[2],vc[3],vc[4],vc[5],
                                                      Wq, Wv, e_idx, wqkv);
  convert_wk_kernel<<<(L_*D_*D_)/2048, 256, 0, stream>>>(Wk, wqkv);
  convert_bf16_kernel<<<(L_*D_*D_)/2048, 256, 0, stream>>>(Wo, wobf);

  for (int l = 0; l < L_; ++l) {
    gemm_bt<true><<<dim3(18,128), 256, 0, stream>>>(xbf, wqkv + (size_t)l*2304*D_,
        bq + l*D_, bk + l*D_, bv + l*D_, qkv, vt, 2304);
    flash_kernel<<<3072, 256, 0, stream>>>(qkv, vt, ctx);
    gemm_bt<false><<<dim3(6,128), 256, 0, stream>>>(ctx, wobf + (size_t)l*D_*D_,
        bo + l*D_, nullptr, nullptr, projb, nullptr, 768);
    if (l == 0)
      ln_kernel<true,false><<<BS_/4, 256, 0, stream>>>(hidden, xbf, projb,
          lns + l*D_, lnb + l*D_, nullptr);
    else if (l == L_-1)
      ln_kernel<false,true><<<BS_/4, 256, 0, stream>>>(nullptr, xbf, projb,
          lns + l*D_, lnb + l*D_, out);
    else
      ln_kernel<false,false><<<BS_/4, 256, 0, stream>>>(nullptr, xbf, projb,
          lns + l*D_, lnb + l*D_, nullptr);
  }
}